// Round 1
// baseline (700.724 us; speedup 1.0000x reference)
//
#include <hip/hip_runtime.h>
#include <hip/hip_bf16.h>
#include <stdint.h>

typedef __bf16 bf16;
typedef __attribute__((ext_vector_type(8))) __bf16 bf16x8;
typedef __attribute__((ext_vector_type(4))) __bf16 bf16x4;
typedef __attribute__((ext_vector_type(4))) float f32x4;

#define S_LEN 2048
#define HDIM  4096
#define NQH   32
#define NKVH  8
#define DHEAD 128
#define QKVN  6144   /* 4096 Q + 1024 K + 1024 V */
#define KOFF  4096
#define VOFF  5120

__device__ __forceinline__ void gload_lds16(const bf16* g, bf16* l) {
  __builtin_amdgcn_global_load_lds(
      (const __attribute__((address_space(1))) unsigned int*)g,
      (__attribute__((address_space(3))) unsigned int*)l, 16, 0, 0);
}

// ---------------------------------------------------------------- f32 -> bf16
__global__ __launch_bounds__(256) void cvt_f32_bf16(const float* __restrict__ in,
                                                    bf16* __restrict__ out, int n4) {
  int i = blockIdx.x * 256 + threadIdx.x;
  if (i >= n4) return;
  float4 v = ((const float4*)in)[i];
  bf16x4 ov = {(bf16)v.x, (bf16)v.y, (bf16)v.z, (bf16)v.w};
  *(bf16x4*)&out[(size_t)i * 4] = ov;
}

// ---------------------------------------------------------------- RoPE table
__global__ __launch_bounds__(256) void rope_table(const int* __restrict__ pos,
                                                  float* __restrict__ tab) {
  int idx = blockIdx.x * 256 + threadIdx.x;  // 2048*64
  int i = idx & 63, s = idx >> 6;
  float p = (float)pos[s];
  float invf = powf(10000.0f, -(float)i * (1.0f / 64.0f));
  float ang = p * invf;
  tab[idx * 2]     = cosf(ang);
  tab[idx * 2 + 1] = sinf(ang);
}

// ---------------------------------------------------------------- RoPE apply (in-place on Q,K cols of QKV)
__global__ __launch_bounds__(256) void rope_apply(bf16* __restrict__ QKV,
                                                  const float* __restrict__ tab) {
  int idx = blockIdx.x * 256 + threadIdx.x;  // 2048*40*64
  int dp = idx & 63;
  int t = idx >> 6;
  int head = t % 40;          // 0..31 = Q heads, 32..39 = K heads
  int s = t / 40;
  float c  = tab[(s * 64 + dp) * 2];
  float sn = tab[(s * 64 + dp) * 2 + 1];
  size_t base = (size_t)s * QKVN + head * DHEAD;
  float x0 = (float)QKV[base + dp];
  float x1 = (float)QKV[base + 64 + dp];
  QKV[base + dp]      = (bf16)(x0 * c - x1 * sn);
  QKV[base + 64 + dp] = (bf16)(x1 * c + x0 * sn);
}

// ---------------------------------------------------------------- V transpose: QKV V-cols -> Vt[kvh*128+d][s]
__global__ __launch_bounds__(256) void transpose_v(const bf16* __restrict__ QKV,
                                                   bf16* __restrict__ Vt) {
  __shared__ bf16 t[64][72];
  int tid = threadIdx.x;
  int bs = blockIdx.x * 64, bc = blockIdx.y * 64;
  int sl = tid >> 3, cb = (tid & 7) * 8;
#pragma unroll
  for (int ss = 0; ss < 64; ss += 32) {
    int s = sl + ss;
    *(bf16x8*)&t[s][cb] = *(const bf16x8*)&QKV[(size_t)(bs + s) * QKVN + VOFF + bc + cb];
  }
  __syncthreads();
  int cl = tid >> 3, sb = (tid & 7) * 8;
#pragma unroll
  for (int cc = 0; cc < 64; cc += 32) {
    int c = cl + cc;
    bf16x8 v;
#pragma unroll
    for (int k = 0; k < 8; ++k) v[k] = t[sb + k][c];
    *(bf16x8*)&Vt[(size_t)(bc + c) * S_LEN + bs + sb] = v;
  }
}

// ---------------------------------------------------------------- GEMM: C[M,N] = A[M,K] * B[N,K]^T  (bf16 in, OutT out)
// 128x128 tile, BK=64, 4 waves (2x2 of 64x64), global_load_lds staging,
// XOR-swizzled LDS (chunk ^= row&7) for conflict-free ds_read_b128.
template <typename OutT>
__global__ __launch_bounds__(256) void gemm_bt(const bf16* __restrict__ A,
                                               const bf16* __restrict__ B,
                                               OutT* __restrict__ C,
                                               int M, int N, int K) {
  __shared__ bf16 At[128 * 64];
  __shared__ bf16 Bt[128 * 64];
  const int tid = threadIdx.x;
  const int w = tid >> 6, lane = tid & 63;
  const int r = lane & 15, g = lane >> 4;
  const int bm = blockIdx.y * 128, bn = blockIdx.x * 128;
  const int wm = (w >> 1) * 64, wn = (w & 1) * 64;
  f32x4 acc[4][4];
#pragma unroll
  for (int i = 0; i < 4; ++i)
#pragma unroll
    for (int j = 0; j < 4; ++j) acc[i][j] = (f32x4){0.f, 0.f, 0.f, 0.f};

  const int chunk0 = w * 256 + lane;  // + i*64

  for (int k0 = 0; k0 < K; k0 += 64) {
#pragma unroll
    for (int i = 0; i < 4; ++i) {
      int chunk = chunk0 + i * 64;
      int row = chunk >> 3, c8 = chunk & 7;
      int cs = ((c8 ^ (row & 7)) << 3) + k0;  // inverse-swizzled global source
      gload_lds16(&A[(size_t)(bm + row) * K + cs], &At[(w * 4 + i) * 512]);
      gload_lds16(&B[(size_t)(bn + row) * K + cs], &Bt[(w * 4 + i) * 512]);
    }
    __syncthreads();  // drains vmcnt -> tile ready
#pragma unroll
    for (int ks = 0; ks < 2; ++ks) {
      bf16x8 af[4], bfr[4];
#pragma unroll
      for (int mi = 0; mi < 4; ++mi) {
        int row = wm + mi * 16 + r;
        af[mi] = *(const bf16x8*)&At[row * 64 + ((((ks << 2) + g) ^ (row & 7)) << 3)];
      }
#pragma unroll
      for (int nj = 0; nj < 4; ++nj) {
        int row = wn + nj * 16 + r;
        bfr[nj] = *(const bf16x8*)&Bt[row * 64 + ((((ks << 2) + g) ^ (row & 7)) << 3)];
      }
#pragma unroll
      for (int mi = 0; mi < 4; ++mi)
#pragma unroll
        for (int nj = 0; nj < 4; ++nj)
          acc[mi][nj] = __builtin_amdgcn_mfma_f32_16x16x32_bf16(af[mi], bfr[nj],
                                                                acc[mi][nj], 0, 0, 0);
    }
    __syncthreads();  // all reads done before next stage overwrites
  }
#pragma unroll
  for (int mi = 0; mi < 4; ++mi)
#pragma unroll
    for (int nj = 0; nj < 4; ++nj)
#pragma unroll
      for (int j = 0; j < 4; ++j) {
        int row = bm + wm + mi * 16 + g * 4 + j;  // C/D: row=(lane>>4)*4+reg
        int col = bn + wn + nj * 16 + r;          //      col=lane&15
        C[(size_t)row * N + col] = (OutT)acc[mi][nj][j];
      }
}

// ---------------------------------------------------------------- flash attention
// grid = (S/16, NKVH). Block = 4 waves; wave w handles q-head kvh*4+w over the
// same 16 q-rows. KV tiles of 32, online softmax, PV via Vt (contiguous-K B-frag).
__global__ __launch_bounds__(256) void attn_kernel(const bf16* __restrict__ QKV,
                                                   const bf16* __restrict__ Vt,
                                                   bf16* __restrict__ Oout) {
  __shared__ bf16 Pl[4][16 * 32];
  const int tid = threadIdx.x;
  const int w = tid >> 6, lane = tid & 63;
  const int r = lane & 15, g = lane >> 4;
  const int q0 = blockIdx.x * 16;
  const int kvh = blockIdx.y;
  const int h = kvh * 4 + w;
  const float scale = 0.08838834764831845f;  // 1/sqrt(128)
  const float MASKNEG = -1e30f;

  bf16x8 aq[4];
#pragma unroll
  for (int ds = 0; ds < 4; ++ds)
    aq[ds] = *(const bf16x8*)&QKV[(size_t)(q0 + r) * QKVN + h * DHEAD + ds * 32 + g * 8];

  f32x4 o[8];
#pragma unroll
  for (int db = 0; db < 8; ++db) o[db] = (f32x4){0.f, 0.f, 0.f, 0.f};
  float m_run[4], l_run[4];
#pragma unroll
  for (int j = 0; j < 4; ++j) { m_run[j] = MASKNEG; l_run[j] = 0.f; }

  const int qmax = q0 + 15;
  for (int kv0 = 0; kv0 <= qmax; kv0 += 32) {
    f32x4 sacc[2];
    sacc[0] = (f32x4){0.f, 0.f, 0.f, 0.f};
    sacc[1] = (f32x4){0.f, 0.f, 0.f, 0.f};
#pragma unroll
    for (int c = 0; c < 2; ++c)
#pragma unroll
      for (int ds = 0; ds < 4; ++ds) {
        bf16x8 kf = *(const bf16x8*)&QKV[(size_t)(kv0 + 16 * c + r) * QKVN + KOFF +
                                         kvh * DHEAD + ds * 32 + g * 8];
        sacc[c] = __builtin_amdgcn_mfma_f32_16x16x32_bf16(aq[ds], kf, sacc[c], 0, 0, 0);
      }
    // scale + causal mask; S layout: col = kv0+16c+(lane&15), row-in-tile = g*4+j
    float sv[2][4];
#pragma unroll
    for (int c = 0; c < 2; ++c)
#pragma unroll
      for (int j = 0; j < 4; ++j) {
        int col = kv0 + 16 * c + r;
        int qrow = q0 + g * 4 + j;
        float v = sacc[c][j] * scale;
        sv[c][j] = (col <= qrow) ? v : MASKNEG;
      }
    float corr[4];
#pragma unroll
    for (int j = 0; j < 4; ++j) {
      float pm = fmaxf(sv[0][j], sv[1][j]);
#pragma unroll
      for (int mk = 1; mk < 16; mk <<= 1) pm = fmaxf(pm, __shfl_xor(pm, mk));
      float mnew = fmaxf(m_run[j], pm);
      corr[j] = __expf(m_run[j] - mnew);
      m_run[j] = mnew;
      float p0 = __expf(sv[0][j] - mnew);
      float p1 = __expf(sv[1][j] - mnew);
      sv[0][j] = p0; sv[1][j] = p1;
      float rs = p0 + p1;
#pragma unroll
      for (int mk = 1; mk < 16; mk <<= 1) rs += __shfl_xor(rs, mk);
      l_run[j] = l_run[j] * corr[j] + rs;
    }
#pragma unroll
    for (int db = 0; db < 8; ++db)
#pragma unroll
      for (int j = 0; j < 4; ++j) o[db][j] *= corr[j];
    // P -> LDS (bf16, chunk-swizzled) so PV A-frag is a contiguous ds_read_b128
#pragma unroll
    for (int c = 0; c < 2; ++c)
#pragma unroll
      for (int j = 0; j < 4; ++j) {
        int row = g * 4 + j;
        int col = 16 * c + r;
        Pl[w][row * 32 + (((col >> 3) ^ (row & 3)) << 3) + (col & 7)] = (bf16)sv[c][j];
      }
    __syncthreads();
    bf16x8 pa = *(const bf16x8*)&Pl[w][r * 32 + ((g ^ (r & 3)) << 3)];
#pragma unroll
    for (int db = 0; db < 8; ++db) {
      bf16x8 vf = *(const bf16x8*)&Vt[(size_t)(kvh * DHEAD + db * 16 + r) * S_LEN + kv0 + g * 8];
      o[db] = __builtin_amdgcn_mfma_f32_16x16x32_bf16(pa, vf, o[db], 0, 0, 0);
    }
    __syncthreads();
  }
#pragma unroll
  for (int db = 0; db < 8; ++db)
#pragma unroll
    for (int j = 0; j < 4; ++j) {
      int srow = q0 + g * 4 + j;
      int col = h * DHEAD + db * 16 + r;
      Oout[(size_t)srow * HDIM + col] = (bf16)(o[db][j] / l_run[j]);
    }
}

// ---------------------------------------------------------------- launcher
extern "C" void kernel_launch(void* const* d_in, const int* in_sizes, int n_in,
                              void* d_out, int out_size, void* d_ws, size_t ws_size,
                              hipStream_t stream) {
  const float* X   = (const float*)d_in[0];
  const int*   pos = (const int*)d_in[1];
  const float* Wq  = (const float*)d_in[2];
  const float* Wk  = (const float*)d_in[3];
  const float* Wv  = (const float*)d_in[4];
  const float* Wo  = (const float*)d_in[5];
  float* out = (float*)d_out;
  char* ws = (char*)d_ws;

  size_t off = 0;
  bf16* Xb    = (bf16*)(ws + off); off += (size_t)2048 * 4096 * 2;
  bf16* Wqkvb = (bf16*)(ws + off); off += (size_t)6144 * 4096 * 2;
  bf16* Wob   = (bf16*)(ws + off); off += (size_t)4096 * 4096 * 2;
  bf16* QKV   = (bf16*)(ws + off); off += (size_t)2048 * 6144 * 2;
  bf16* Vt    = (bf16*)(ws + off); off += (size_t)1024 * 2048 * 2;
  bf16* attnb = (bf16*)(ws + off); off += (size_t)2048 * 4096 * 2;
  float* tab  = (float*)(ws + off); off += (size_t)2048 * 64 * 2 * 4;

  cvt_f32_bf16<<<2048 * 4096 / 4 / 256, 256, 0, stream>>>(X, Xb, 2048 * 4096 / 4);
  cvt_f32_bf16<<<4096 * 4096 / 4 / 256, 256, 0, stream>>>(Wq, Wqkvb, 4096 * 4096 / 4);
  cvt_f32_bf16<<<1024 * 4096 / 4 / 256, 256, 0, stream>>>(Wk, Wqkvb + (size_t)4096 * 4096,
                                                          1024 * 4096 / 4);
  cvt_f32_bf16<<<1024 * 4096 / 4 / 256, 256, 0, stream>>>(Wv, Wqkvb + (size_t)5120 * 4096,
                                                          1024 * 4096 / 4);
  cvt_f32_bf16<<<4096 * 4096 / 4 / 256, 256, 0, stream>>>(Wo, Wob, 4096 * 4096 / 4);
  rope_table<<<2048 * 64 / 256, 256, 0, stream>>>(pos, tab);
  gemm_bt<bf16><<<dim3(QKVN / 128, 2048 / 128), 256, 0, stream>>>(Xb, Wqkvb, QKV,
                                                                  2048, QKVN, 4096);
  rope_apply<<<2048 * 40 * 64 / 256, 256, 0, stream>>>(QKV, tab);
  transpose_v<<<dim3(2048 / 64, 1024 / 64), 256, 0, stream>>>(QKV, Vt);
  attn_kernel<<<dim3(2048 / 16, NKVH), 256, 0, stream>>>(QKV, Vt, attnb);
  gemm_bt<float><<<dim3(4096 / 128, 2048 / 128), 256, 0, stream>>>(attnb, Wob, out,
                                                                   2048, 4096, 4096);
}

// Round 2
// 535.062 us; speedup vs baseline: 1.3096x; 1.3096x over previous
//
#include <hip/hip_runtime.h>
#include <hip/hip_bf16.h>
#include <stdint.h>

typedef __bf16 bf16;
typedef __attribute__((ext_vector_type(8))) __bf16 bf16x8;
typedef __attribute__((ext_vector_type(4))) __bf16 bf16x4;
typedef __attribute__((ext_vector_type(4))) float f32x4;
typedef __attribute__((ext_vector_type(16))) float f32x16;

#define S_LEN 2048
#define HDIM  4096
#define NQH   32
#define NKVH  8
#define DHEAD 128
#define QKVN  6144   /* 4096 Q + 1024 K + 1024 V */
#define KOFF  4096
#define VOFF  5120

__device__ __forceinline__ void gload_lds16(const bf16* g, bf16* l) {
  __builtin_amdgcn_global_load_lds(
      (const __attribute__((address_space(1))) unsigned int*)g,
      (__attribute__((address_space(3))) unsigned int*)l, 16, 0, 0);
}

// ---------------------------------------------------------------- f32 -> bf16
__global__ __launch_bounds__(256) void cvt_f32_bf16(const float* __restrict__ in,
                                                    bf16* __restrict__ out, int n4) {
  int i = blockIdx.x * 256 + threadIdx.x;
  if (i >= n4) return;
  float4 v = ((const float4*)in)[i];
  bf16x4 ov = {(bf16)v.x, (bf16)v.y, (bf16)v.z, (bf16)v.w};
  *(bf16x4*)&out[(size_t)i * 4] = ov;
}

// ---------------------------------------------------------------- RoPE table
__global__ __launch_bounds__(256) void rope_table(const int* __restrict__ pos,
                                                  float* __restrict__ tab) {
  int idx = blockIdx.x * 256 + threadIdx.x;  // 2048*64
  int i = idx & 63, s = idx >> 6;
  float p = (float)pos[s];
  float invf = powf(10000.0f, -(float)i * (1.0f / 64.0f));
  float ang = p * invf;
  tab[idx * 2]     = cosf(ang);
  tab[idx * 2 + 1] = sinf(ang);
}

// ---------------------------------------------------------------- RoPE apply (in-place on Q,K cols of QKV)
__global__ __launch_bounds__(256) void rope_apply(bf16* __restrict__ QKV,
                                                  const float* __restrict__ tab) {
  int idx = blockIdx.x * 256 + threadIdx.x;  // 2048*40*64
  int dp = idx & 63;
  int t = idx >> 6;
  int head = t % 40;          // 0..31 = Q heads, 32..39 = K heads
  int s = t / 40;
  float c  = tab[(s * 64 + dp) * 2];
  float sn = tab[(s * 64 + dp) * 2 + 1];
  size_t base = (size_t)s * QKVN + head * DHEAD;
  float x0 = (float)QKV[base + dp];
  float x1 = (float)QKV[base + 64 + dp];
  QKV[base + dp]      = (bf16)(x0 * c - x1 * sn);
  QKV[base + 64 + dp] = (bf16)(x1 * c + x0 * sn);
}

// ---------------------------------------------------------------- V transpose: QKV V-cols -> Vt[kvh*128+d][s]
__global__ __launch_bounds__(256) void transpose_v(const bf16* __restrict__ QKV,
                                                   bf16* __restrict__ Vt) {
  __shared__ bf16 t[64][72];
  int tid = threadIdx.x;
  int bs = blockIdx.x * 64, bc = blockIdx.y * 64;
  int sl = tid >> 3, cb = (tid & 7) * 8;
#pragma unroll
  for (int ss = 0; ss < 64; ss += 32) {
    int s = sl + ss;
    *(bf16x8*)&t[s][cb] = *(const bf16x8*)&QKV[(size_t)(bs + s) * QKVN + VOFF + bc + cb];
  }
  __syncthreads();
  int cl = tid >> 3, sb = (tid & 7) * 8;
#pragma unroll
  for (int cc = 0; cc < 64; cc += 32) {
    int c = cl + cc;
    bf16x8 v;
#pragma unroll
    for (int k = 0; k < 8; ++k) v[k] = t[sb + k][c];
    *(bf16x8*)&Vt[(size_t)(bc + c) * S_LEN + bs + sb] = v;
  }
}

// ---------------------------------------------------------------- GEMM: C[M,N] = A[M,K] * B[N,K]^T  (bf16 in, OutT out)
// 128x128 tile, BK=64, 4 waves (2x2 of 64x64), global_load_lds staging,
// XOR-swizzled LDS (chunk ^= row&7) for conflict-free ds_read_b128.
template <typename OutT>
__global__ __launch_bounds__(256) void gemm_bt(const bf16* __restrict__ A,
                                               const bf16* __restrict__ B,
                                               OutT* __restrict__ C,
                                               int M, int N, int K) {
  __shared__ bf16 At[128 * 64];
  __shared__ bf16 Bt[128 * 64];
  const int tid = threadIdx.x;
  const int w = tid >> 6, lane = tid & 63;
  const int r = lane & 15, g = lane >> 4;
  const int bm = blockIdx.y * 128, bn = blockIdx.x * 128;
  const int wm = (w >> 1) * 64, wn = (w & 1) * 64;
  f32x4 acc[4][4];
#pragma unroll
  for (int i = 0; i < 4; ++i)
#pragma unroll
    for (int j = 0; j < 4; ++j) acc[i][j] = (f32x4){0.f, 0.f, 0.f, 0.f};

  const int chunk0 = w * 256 + lane;  // + i*64

  for (int k0 = 0; k0 < K; k0 += 64) {
#pragma unroll
    for (int i = 0; i < 4; ++i) {
      int chunk = chunk0 + i * 64;
      int row = chunk >> 3, c8 = chunk & 7;
      int cs = ((c8 ^ (row & 7)) << 3) + k0;  // inverse-swizzled global source
      gload_lds16(&A[(size_t)(bm + row) * K + cs], &At[(w * 4 + i) * 512]);
      gload_lds16(&B[(size_t)(bn + row) * K + cs], &Bt[(w * 4 + i) * 512]);
    }
    __syncthreads();  // drains vmcnt -> tile ready
#pragma unroll
    for (int ks = 0; ks < 2; ++ks) {
      bf16x8 af[4], bfr[4];
#pragma unroll
      for (int mi = 0; mi < 4; ++mi) {
        int row = wm + mi * 16 + r;
        af[mi] = *(const bf16x8*)&At[row * 64 + ((((ks << 2) + g) ^ (row & 7)) << 3)];
      }
#pragma unroll
      for (int nj = 0; nj < 4; ++nj) {
        int row = wn + nj * 16 + r;
        bfr[nj] = *(const bf16x8*)&Bt[row * 64 + ((((ks << 2) + g) ^ (row & 7)) << 3)];
      }
#pragma unroll
      for (int mi = 0; mi < 4; ++mi)
#pragma unroll
        for (int nj = 0; nj < 4; ++nj)
          acc[mi][nj] = __builtin_amdgcn_mfma_f32_16x16x32_bf16(af[mi], bfr[nj],
                                                                acc[mi][nj], 0, 0, 0);
    }
    __syncthreads();  // all reads done before next stage overwrites
  }
#pragma unroll
  for (int mi = 0; mi < 4; ++mi)
#pragma unroll
    for (int nj = 0; nj < 4; ++nj)
#pragma unroll
      for (int j = 0; j < 4; ++j) {
        int row = bm + wm + mi * 16 + g * 4 + j;  // C/D: row=(lane>>4)*4+reg
        int col = bn + wn + nj * 16 + r;          //      col=lane&15
        C[(size_t)row * N + col] = (OutT)acc[mi][nj][j];
      }
}

// ---------------------------------------------------------------- flash attention (swapped-QK^T, in-register softmax)
// grid = (S/32, NKVH). Block = 4 waves; wave w handles q-head kvh*4+w over the
// same 32 q-rows (identical K/V addresses across waves -> L1 reuse, no LDS).
// QK^T computed as mfma(K, Q) -> S^T: lane owns one q-row (q = lane&31),
// kv = (reg&3)+8*(reg>>2)+4*hi. Softmax fully per-lane. PV via in-register
// P repack (shfl_xor across halves) feeding 32x32x16 MFMAs with Vt[d][s].
__global__ __launch_bounds__(256) void attn_kernel(const bf16* __restrict__ QKV,
                                                   const bf16* __restrict__ Vt,
                                                   bf16* __restrict__ Oout) {
  const int tid = threadIdx.x;
  const int w = tid >> 6, lane = tid & 63;
  const int l31 = lane & 31, hi = lane >> 5;
  const int q0 = blockIdx.x * 32;
  const int kvh = blockIdx.y;
  const int h = kvh * 4 + w;
  const float scale = 0.08838834764831845f;  // 1/sqrt(128)

  // Q B-fragments, pre-scaled: B col=lane&31=q, k=hi*8+j (per 16-k chunk)
  bf16x8 qf[8];
#pragma unroll
  for (int k8 = 0; k8 < 8; ++k8) {
    bf16x8 raw = *(const bf16x8*)&QKV[(size_t)(q0 + l31) * QKVN + h * DHEAD + k8 * 16 + hi * 8];
#pragma unroll
    for (int e = 0; e < 8; ++e) qf[k8][e] = (bf16)((float)raw[e] * scale);
  }

  f32x16 o[4];
#pragma unroll
  for (int t = 0; t < 4; ++t)
#pragma unroll
    for (int r = 0; r < 16; ++r) o[t][r] = 0.f;
  float m_run = -1e30f, l_run = 0.f;

  for (int kv0 = 0; kv0 <= q0; kv0 += 32) {
    // ---- QK^T (swapped): st = K_tile * Q^T, st[reg] = S^T[kv(reg,hi)][q=lane&31]
    f32x16 st;
#pragma unroll
    for (int r = 0; r < 16; ++r) st[r] = 0.f;
#pragma unroll
    for (int k8 = 0; k8 < 8; ++k8) {
      bf16x8 kf = *(const bf16x8*)&QKV[(size_t)(kv0 + l31) * QKVN + KOFF +
                                       kvh * DHEAD + k8 * 16 + hi * 8];
      st = __builtin_amdgcn_mfma_f32_32x32x16_bf16(kf, qf[k8], st, 0, 0, 0);
    }
    // ---- causal mask: only the diagonal tile needs it
    if (kv0 == q0) {
#pragma unroll
      for (int r = 0; r < 16; ++r) {
        int kvr = (r & 3) + 8 * (r >> 2) + 4 * hi;
        if (kvr > l31) st[r] = -1e30f;
      }
    }
    // ---- per-lane online softmax (lane owns a full q-row slice)
    float pmax = st[0];
#pragma unroll
    for (int r = 1; r < 16; ++r) pmax = fmaxf(pmax, st[r]);
    pmax = fmaxf(pmax, __shfl_xor(pmax, 32));
    if (!__all(pmax - m_run <= 8.0f)) {  // T13 defer-max
      float mnew = fmaxf(m_run, pmax);
      float corr = __expf(m_run - mnew);
      m_run = mnew;
      l_run *= corr;
#pragma unroll
      for (int r = 0; r < 16; ++r) {
        float cr = __shfl(corr, (r & 3) + 8 * (r >> 2) + 4 * hi);
        o[0][r] *= cr; o[1][r] *= cr; o[2][r] *= cr; o[3][r] *= cr;
      }
    }
    float p[16], rs = 0.f;
#pragma unroll
    for (int r = 0; r < 16; ++r) { p[r] = __expf(st[r] - m_run); rs += p[r]; }
    rs += __shfl_xor(rs, 32);
    l_run += rs;
    // ---- repack P (f32, lane-local) into PV A-fragments (bf16) via half-swap
    float sp[16];
#pragma unroll
    for (int i = 0; i < 16; ++i) sp[i] = __shfl_xor(p[i], 32);
    bf16x8 pf0, pf1;
#pragma unroll
    for (int e = 0; e < 4; ++e) {
      pf0[e]     = (bf16)(hi ? sp[4 + e]  : p[e]);
      pf0[e + 4] = (bf16)(hi ? p[4 + e]   : sp[e]);
      pf1[e]     = (bf16)(hi ? sp[12 + e] : p[8 + e]);
      pf1[e + 4] = (bf16)(hi ? p[12 + e]  : sp[8 + e]);
    }
    // ---- PV: O[q, d] += P * V, B-frag from Vt[d][s] (contiguous 16B)
#pragma unroll
    for (int t = 0; t < 4; ++t) {
      const bf16* vb = &Vt[(size_t)(kvh * DHEAD + t * 32 + l31) * S_LEN + kv0 + hi * 8];
      o[t] = __builtin_amdgcn_mfma_f32_32x32x16_bf16(pf0, *(const bf16x8*)vb, o[t], 0, 0, 0);
      o[t] = __builtin_amdgcn_mfma_f32_32x32x16_bf16(pf1, *(const bf16x8*)(vb + 16), o[t], 0, 0, 0);
    }
  }
  // ---- epilogue: divide by l (broadcast per output row), store
  float linv = 1.0f / l_run;
#pragma unroll
  for (int r = 0; r < 16; ++r) {
    int qloc = (r & 3) + 8 * (r >> 2) + 4 * hi;
    float li = __shfl(linv, qloc);
    size_t row = (size_t)(q0 + qloc) * HDIM + h * DHEAD;
#pragma unroll
    for (int t = 0; t < 4; ++t)
      Oout[row + t * 32 + l31] = (bf16)(o[t][r] * li);
  }
}

// ---------------------------------------------------------------- launcher
extern "C" void kernel_launch(void* const* d_in, const int* in_sizes, int n_in,
                              void* d_out, int out_size, void* d_ws, size_t ws_size,
                              hipStream_t stream) {
  const float* X   = (const float*)d_in[0];
  const int*   pos = (const int*)d_in[1];
  const float* Wq  = (const float*)d_in[2];
  const float* Wk  = (const float*)d_in[3];
  const float* Wv  = (const float*)d_in[4];
  const float* Wo  = (const float*)d_in[5];
  float* out = (float*)d_out;
  char* ws = (char*)d_ws;

  size_t off = 0;
  bf16* Xb    = (bf16*)(ws + off); off += (size_t)2048 * 4096 * 2;
  bf16* Wqkvb = (bf16*)(ws + off); off += (size_t)6144 * 4096 * 2;
  bf16* Wob   = (bf16*)(ws + off); off += (size_t)4096 * 4096 * 2;
  bf16* QKV   = (bf16*)(ws + off); off += (size_t)2048 * 6144 * 2;
  bf16* Vt    = (bf16*)(ws + off); off += (size_t)1024 * 2048 * 2;
  bf16* attnb = (bf16*)(ws + off); off += (size_t)2048 * 4096 * 2;
  float* tab  = (float*)(ws + off); off += (size_t)2048 * 64 * 2 * 4;

  cvt_f32_bf16<<<2048 * 4096 / 4 / 256, 256, 0, stream>>>(X, Xb, 2048 * 4096 / 4);
  cvt_f32_bf16<<<4096 * 4096 / 4 / 256, 256, 0, stream>>>(Wq, Wqkvb, 4096 * 4096 / 4);
  cvt_f32_bf16<<<1024 * 4096 / 4 / 256, 256, 0, stream>>>(Wk, Wqkvb + (size_t)4096 * 4096,
                                                          1024 * 4096 / 4);
  cvt_f32_bf16<<<1024 * 4096 / 4 / 256, 256, 0, stream>>>(Wv, Wqkvb + (size_t)5120 * 4096,
                                                          1024 * 4096 / 4);
  cvt_f32_bf16<<<4096 * 4096 / 4 / 256, 256, 0, stream>>>(Wo, Wob, 4096 * 4096 / 4);
  rope_table<<<2048 * 64 / 256, 256, 0, stream>>>(pos, tab);
  gemm_bt<bf16><<<dim3(QKVN / 128, 2048 / 128), 256, 0, stream>>>(Xb, Wqkvb, QKV,
                                                                  2048, QKVN, 4096);
  rope_apply<<<2048 * 40 * 64 / 256, 256, 0, stream>>>(QKV, tab);
  transpose_v<<<dim3(2048 / 64, 1024 / 64), 256, 0, stream>>>(QKV, Vt);
  attn_kernel<<<dim3(2048 / 32, NKVH), 256, 0, stream>>>(QKV, Vt, attnb);
  gemm_bt<float><<<dim3(4096 / 128, 2048 / 128), 256, 0, stream>>>(attnb, Wob, out,
                                                                   2048, 4096, 4096);
}

// Round 3
// 420.988 us; speedup vs baseline: 1.6645x; 1.2710x over previous
//
#include <hip/hip_runtime.h>
#include <hip/hip_bf16.h>
#include <stdint.h>

typedef __bf16 bf16;
typedef __attribute__((ext_vector_type(8))) __bf16 bf16x8;
typedef __attribute__((ext_vector_type(4))) __bf16 bf16x4;
typedef __attribute__((ext_vector_type(4))) float f32x4;
typedef __attribute__((ext_vector_type(16))) float f32x16;

#define S_LEN 2048
#define HDIM  4096
#define NQH   32
#define NKVH  8
#define DHEAD 128
#define QKVN  6144   /* 4096 Q + 1024 K + 1024 V */
#define KOFF  4096
#define VOFF  5120

__device__ __forceinline__ void gload_lds16(const bf16* g, bf16* l) {
  __builtin_amdgcn_global_load_lds(
      (const __attribute__((address_space(1))) unsigned int*)g,
      (__attribute__((address_space(3))) unsigned int*)l, 16, 0, 0);
}

// ---------------------------------------------------------------- f32 -> bf16
__global__ __launch_bounds__(256) void cvt_f32_bf16(const float* __restrict__ in,
                                                    bf16* __restrict__ out, int n4) {
  int i = blockIdx.x * 256 + threadIdx.x;
  if (i >= n4) return;
  float4 v = ((const float4*)in)[i];
  bf16x4 ov = {(bf16)v.x, (bf16)v.y, (bf16)v.z, (bf16)v.w};
  *(bf16x4*)&out[(size_t)i * 4] = ov;
}

// ---------------------------------------------------------------- RoPE table
__global__ __launch_bounds__(256) void rope_table(const int* __restrict__ pos,
                                                  float* __restrict__ tab) {
  int idx = blockIdx.x * 256 + threadIdx.x;  // 2048*64
  int i = idx & 63, s = idx >> 6;
  float p = (float)pos[s];
  float invf = powf(10000.0f, -(float)i * (1.0f / 64.0f));
  float ang = p * invf;
  tab[idx * 2]     = cosf(ang);
  tab[idx * 2 + 1] = sinf(ang);
}

// ---------------------------------------------------------------- RoPE apply (in-place on Q,K cols of QKV)
__global__ __launch_bounds__(256) void rope_apply(bf16* __restrict__ QKV,
                                                  const float* __restrict__ tab) {
  int idx = blockIdx.x * 256 + threadIdx.x;  // 2048*40*64
  int dp = idx & 63;
  int t = idx >> 6;
  int head = t % 40;          // 0..31 = Q heads, 32..39 = K heads
  int s = t / 40;
  float c  = tab[(s * 64 + dp) * 2];
  float sn = tab[(s * 64 + dp) * 2 + 1];
  size_t base = (size_t)s * QKVN + head * DHEAD;
  float x0 = (float)QKV[base + dp];
  float x1 = (float)QKV[base + 64 + dp];
  QKV[base + dp]      = (bf16)(x0 * c - x1 * sn);
  QKV[base + 64 + dp] = (bf16)(x1 * c + x0 * sn);
}

// ---------------------------------------------------------------- V transpose: QKV V-cols -> Vt[kvh*128+d][s]
__global__ __launch_bounds__(256) void transpose_v(const bf16* __restrict__ QKV,
                                                   bf16* __restrict__ Vt) {
  __shared__ bf16 t[64][72];
  int tid = threadIdx.x;
  int bs = blockIdx.x * 64, bc = blockIdx.y * 64;
  int sl = tid >> 3, cb = (tid & 7) * 8;
#pragma unroll
  for (int ss = 0; ss < 64; ss += 32) {
    int s = sl + ss;
    *(bf16x8*)&t[s][cb] = *(const bf16x8*)&QKV[(size_t)(bs + s) * QKVN + VOFF + bc + cb];
  }
  __syncthreads();
  int cl = tid >> 3, sb = (tid & 7) * 8;
#pragma unroll
  for (int cc = 0; cc < 64; cc += 32) {
    int c = cl + cc;
    bf16x8 v;
#pragma unroll
    for (int k = 0; k < 8; ++k) v[k] = t[sb + k][c];
    *(bf16x8*)&Vt[(size_t)(bc + c) * S_LEN + bs + sb] = v;
  }
}

// ---------------------------------------------------------------- GEMM: C[M,N] = A[M,K] * B[N,K]^T  (bf16 in, OutT out)
// 128x128 tile, BK=64, 4 waves (2x2 of 64x64), global_load_lds staging,
// XOR-swizzled LDS (chunk ^= row&7) for conflict-free ds_read_b128.
template <typename OutT>
__global__ __launch_bounds__(256) void gemm_bt(const bf16* __restrict__ A,
                                               const bf16* __restrict__ B,
                                               OutT* __restrict__ C,
                                               int M, int N, int K) {
  __shared__ bf16 At[128 * 64];
  __shared__ bf16 Bt[128 * 64];
  const int tid = threadIdx.x;
  const int w = tid >> 6, lane = tid & 63;
  const int r = lane & 15, g = lane >> 4;
  const int bm = blockIdx.y * 128, bn = blockIdx.x * 128;
  const int wm = (w >> 1) * 64, wn = (w & 1) * 64;
  f32x4 acc[4][4];
#pragma unroll
  for (int i = 0; i < 4; ++i)
#pragma unroll
    for (int j = 0; j < 4; ++j) acc[i][j] = (f32x4){0.f, 0.f, 0.f, 0.f};

  const int chunk0 = w * 256 + lane;  // + i*64

  for (int k0 = 0; k0 < K; k0 += 64) {
#pragma unroll
    for (int i = 0; i < 4; ++i) {
      int chunk = chunk0 + i * 64;
      int row = chunk >> 3, c8 = chunk & 7;
      int cs = ((c8 ^ (row & 7)) << 3) + k0;  // inverse-swizzled global source
      gload_lds16(&A[(size_t)(bm + row) * K + cs], &At[(w * 4 + i) * 512]);
      gload_lds16(&B[(size_t)(bn + row) * K + cs], &Bt[(w * 4 + i) * 512]);
    }
    __syncthreads();  // drains vmcnt -> tile ready
#pragma unroll
    for (int ks = 0; ks < 2; ++ks) {
      bf16x8 af[4], bfr[4];
#pragma unroll
      for (int mi = 0; mi < 4; ++mi) {
        int row = wm + mi * 16 + r;
        af[mi] = *(const bf16x8*)&At[row * 64 + ((((ks << 2) + g) ^ (row & 7)) << 3)];
      }
#pragma unroll
      for (int nj = 0; nj < 4; ++nj) {
        int row = wn + nj * 16 + r;
        bfr[nj] = *(const bf16x8*)&Bt[row * 64 + ((((ks << 2) + g) ^ (row & 7)) << 3)];
      }
#pragma unroll
      for (int mi = 0; mi < 4; ++mi)
#pragma unroll
        for (int nj = 0; nj < 4; ++nj)
          acc[mi][nj] = __builtin_amdgcn_mfma_f32_16x16x32_bf16(af[mi], bfr[nj],
                                                                acc[mi][nj], 0, 0, 0);
    }
    __syncthreads();  // all reads done before next stage overwrites
  }
#pragma unroll
  for (int mi = 0; mi < 4; ++mi)
#pragma unroll
    for (int nj = 0; nj < 4; ++nj)
#pragma unroll
      for (int j = 0; j < 4; ++j) {
        int row = bm + wm + mi * 16 + g * 4 + j;  // C/D: row=(lane>>4)*4+reg
        int col = bn + wn + nj * 16 + r;          //      col=lane&15
        C[(size_t)row * N + col] = (OutT)acc[mi][nj][j];
      }
}

// ---------------------------------------------------------------- flash attention
// grid = 2048 one-wave blocks (64 q-blocks x 32 heads), heavy-first order.
// Swapped QK^T (mfma(K,Q) -> S^T), fully per-lane softmax in exp2 domain,
// explicit K double-buffer + early V loads for cross/intra-iter overlap.
__global__ __launch_bounds__(64, 2) void attn_kernel(const bf16* __restrict__ QKV,
                                                     const bf16* __restrict__ Vt,
                                                     bf16* __restrict__ Oout) {
  const int lane = threadIdx.x & 63;
  const int l31 = lane & 31, hi = lane >> 5;
  const int qblk = 63 - (blockIdx.x >> 5);   // heavy blocks dispatch first
  const int h = blockIdx.x & 31;
  const int kvh = h >> 2;
  const int q0 = qblk * 32;
  const float scale = 0.12751746f;  // (1/sqrt(128)) * log2(e)  -> exp2-domain softmax

  // Q B-fragments, pre-scaled: B col=lane&31=q, k=hi*8+j (per 16-k chunk)
  bf16x8 qf[8];
#pragma unroll
  for (int k8 = 0; k8 < 8; ++k8) {
    bf16x8 raw = *(const bf16x8*)&QKV[(size_t)(q0 + l31) * QKVN + h * DHEAD + k8 * 16 + hi * 8];
#pragma unroll
    for (int e = 0; e < 8; ++e) qf[k8][e] = (bf16)((float)raw[e] * scale);
  }

  f32x16 o[4];
#pragma unroll
  for (int t = 0; t < 4; ++t)
#pragma unroll
    for (int r = 0; r < 16; ++r) o[t][r] = 0.f;
  float m_run = -1e30f, l_run = 0.f;

  auto loadK = [&](bf16x8 (&kd)[8], int kv0) {
#pragma unroll
    for (int k8 = 0; k8 < 8; ++k8)
      kd[k8] = *(const bf16x8*)&QKV[(size_t)(kv0 + l31) * QKVN + KOFF +
                                    kvh * DHEAD + k8 * 16 + hi * 8];
  };

  auto process = [&](bf16x8 (&kc)[8], bf16x8 (&kn)[8], int kv0, bool pre, bool diag) {
    // V loads issued first: in flight under QK^T + softmax
    bf16x8 vf[8];
#pragma unroll
    for (int t = 0; t < 4; ++t) {
      const bf16* vb = &Vt[(size_t)(kvh * DHEAD + t * 32 + l31) * S_LEN + kv0 + hi * 8];
      vf[2 * t]     = *(const bf16x8*)vb;
      vf[2 * t + 1] = *(const bf16x8*)(vb + 16);
    }
    // QK^T (swapped): st[reg] = S^T[kv(reg,hi)][q=lane&31], already exp2-scaled
    f32x16 st;
#pragma unroll
    for (int r = 0; r < 16; ++r) st[r] = 0.f;
#pragma unroll
    for (int k8 = 0; k8 < 8; ++k8)
      st = __builtin_amdgcn_mfma_f32_32x32x16_bf16(kc[k8], qf[k8], st, 0, 0, 0);
    // prefetch next K tile (independent of everything below)
    if (pre) loadK(kn, kv0 + 32);
    // causal mask: only the diagonal tile
    if (diag) {
#pragma unroll
      for (int r = 0; r < 16; ++r) {
        int kvr = (r & 3) + 8 * (r >> 2) + 4 * hi;
        if (kvr > l31) st[r] = -1e30f;
      }
    }
    // per-lane online softmax (exp2 domain)
    float pmax = st[0];
#pragma unroll
    for (int r = 1; r < 16; ++r) pmax = fmaxf(pmax, st[r]);
    pmax = fmaxf(pmax, __shfl_xor(pmax, 32));
    if (!__all(pmax - m_run <= 8.0f)) {  // T13 defer-max
      float mnew = fmaxf(m_run, pmax);
      float corr = exp2f(m_run - mnew);
      m_run = mnew;
      l_run *= corr;
#pragma unroll
      for (int r = 0; r < 16; ++r) {
        float cr = __shfl(corr, (r & 3) + 8 * (r >> 2) + 4 * hi);
        o[0][r] *= cr; o[1][r] *= cr; o[2][r] *= cr; o[3][r] *= cr;
      }
    }
    float p[16], rs = 0.f;
#pragma unroll
    for (int r = 0; r < 16; ++r) { p[r] = exp2f(st[r] - m_run); rs += p[r]; }
    rs += __shfl_xor(rs, 32);
    l_run += rs;
    // repack P (f32, lane-local) into PV A-fragments (bf16) via half-swap
    float sp[16];
#pragma unroll
    for (int i = 0; i < 16; ++i) sp[i] = __shfl_xor(p[i], 32);
    bf16x8 pf0, pf1;
#pragma unroll
    for (int e = 0; e < 4; ++e) {
      pf0[e]     = (bf16)(hi ? sp[4 + e]  : p[e]);
      pf0[e + 4] = (bf16)(hi ? p[4 + e]   : sp[e]);
      pf1[e]     = (bf16)(hi ? sp[12 + e] : p[8 + e]);
      pf1[e + 4] = (bf16)(hi ? p[12 + e]  : sp[8 + e]);
    }
    // PV: O[q, d] += P * V
#pragma unroll
    for (int t = 0; t < 4; ++t) {
      o[t] = __builtin_amdgcn_mfma_f32_32x32x16_bf16(pf0, vf[2 * t],     o[t], 0, 0, 0);
      o[t] = __builtin_amdgcn_mfma_f32_32x32x16_bf16(pf1, vf[2 * t + 1], o[t], 0, 0, 0);
    }
  };

  const int nt = qblk + 1;  // KV tiles
  bf16x8 kfA[8], kfB[8];
  loadK(kfA, 0);
  int t = 0;
  while (true) {
    process(kfA, kfB, t * 32, t + 1 < nt, t == nt - 1);
    ++t; if (t >= nt) break;
    process(kfB, kfA, t * 32, t + 1 < nt, t == nt - 1);
    ++t; if (t >= nt) break;
  }

  // epilogue: divide by l (broadcast per output row), store
  float linv = 1.0f / l_run;
#pragma unroll
  for (int r = 0; r < 16; ++r) {
    int qloc = (r & 3) + 8 * (r >> 2) + 4 * hi;
    float li = __shfl(linv, qloc);
    size_t row = (size_t)(q0 + qloc) * HDIM + h * DHEAD;
#pragma unroll
    for (int t2 = 0; t2 < 4; ++t2)
      Oout[row + t2 * 32 + l31] = (bf16)(o[t2][r] * li);
  }
}

// ---------------------------------------------------------------- launcher
extern "C" void kernel_launch(void* const* d_in, const int* in_sizes, int n_in,
                              void* d_out, int out_size, void* d_ws, size_t ws_size,
                              hipStream_t stream) {
  const float* X   = (const float*)d_in[0];
  const int*   pos = (const int*)d_in[1];
  const float* Wq  = (const float*)d_in[2];
  const float* Wk  = (const float*)d_in[3];
  const float* Wv  = (const float*)d_in[4];
  const float* Wo  = (const float*)d_in[5];
  float* out = (float*)d_out;
  char* ws = (char*)d_ws;

  size_t off = 0;
  bf16* Xb    = (bf16*)(ws + off); off += (size_t)2048 * 4096 * 2;
  bf16* Wqkvb = (bf16*)(ws + off); off += (size_t)6144 * 4096 * 2;
  bf16* Wob   = (bf16*)(ws + off); off += (size_t)4096 * 4096 * 2;
  bf16* QKV   = (bf16*)(ws + off); off += (size_t)2048 * 6144 * 2;
  bf16* Vt    = (bf16*)(ws + off); off += (size_t)1024 * 2048 * 2;
  bf16* attnb = (bf16*)(ws + off); off += (size_t)2048 * 4096 * 2;
  float* tab  = (float*)(ws + off); off += (size_t)2048 * 64 * 2 * 4;

  cvt_f32_bf16<<<2048 * 4096 / 4 / 256, 256, 0, stream>>>(X, Xb, 2048 * 4096 / 4);
  cvt_f32_bf16<<<4096 * 4096 / 4 / 256, 256, 0, stream>>>(Wq, Wqkvb, 4096 * 4096 / 4);
  cvt_f32_bf16<<<1024 * 4096 / 4 / 256, 256, 0, stream>>>(Wk, Wqkvb + (size_t)4096 * 4096,
                                                          1024 * 4096 / 4);
  cvt_f32_bf16<<<1024 * 4096 / 4 / 256, 256, 0, stream>>>(Wv, Wqkvb + (size_t)5120 * 4096,
                                                          1024 * 4096 / 4);
  cvt_f32_bf16<<<4096 * 4096 / 4 / 256, 256, 0, stream>>>(Wo, Wob, 4096 * 4096 / 4);
  rope_table<<<2048 * 64 / 256, 256, 0, stream>>>(pos, tab);
  gemm_bt<bf16><<<dim3(QKVN / 128, 2048 / 128), 256, 0, stream>>>(Xb, Wqkvb, QKV,
                                                                  2048, QKVN, 4096);
  rope_apply<<<2048 * 40 * 64 / 256, 256, 0, stream>>>(QKV, tab);
  transpose_v<<<dim3(2048 / 64, 1024 / 64), 256, 0, stream>>>(QKV, Vt);
  attn_kernel<<<2048, 64, 0, stream>>>(QKV, Vt, attnb);
  gemm_bt<float><<<dim3(4096 / 128, 2048 / 128), 256, 0, stream>>>(attnb, Wob, out,
                                                                   2048, 4096, 4096);
}